// Round 1
// 108.425 us; speedup vs baseline: 1.0321x; 1.0321x over previous
//
#include <hip/hip_runtime.h>

#define D 256
#define NATOMS 32768
#define NSUP 8192
#define NSTRUCT 512
#define NKC 64   // k-chunks in kA

typedef __attribute__((ext_vector_type(8))) short short8;
typedef __attribute__((ext_vector_type(4))) float floatx4;

__device__ __forceinline__ unsigned short f2bf(float f) {
    unsigned int u = __float_as_uint(f);
    u += 0x7FFF + ((u >> 16) & 1);   // round-to-nearest-even
    return (unsigned short)(u >> 16);
}
__device__ __forceinline__ float bf2f(unsigned short h) {
    return __uint_as_float(((unsigned int)h) << 16);
}

// ws layout (bytes): Mpart fp32 [NKC][65536] at 0 (16 MB) | Mswz u16 at 16777216 (128 KB)

// M partials: Mpart[kc][a][b] = sum_{j in chunk kc} w[colseg[j]]*S[j][a]*S[j][b],
// upper slab-triangle only. Wave = 32x32 tile, K-chunk 128. NON-ATOMIC stores to
// disjoint (pair,kchunk) regions. 36 pairs x 64 kchunks = 2304 waves = 576 blocks
// (~2.25 blocks/CU -> 2-3 waves/SIMD of latency hiding vs 1 before).
__global__ __launch_bounds__(256) void kA_buildM(const float* __restrict__ S,
                                                 const float* __restrict__ weights,
                                                 const int* __restrict__ colseg,
                                                 float* __restrict__ Mpart) {
    const int tid = threadIdx.x;
    const int l = tid & 63, w = tid >> 6;
    const int wid = blockIdx.x * 4 + w;           // 0..2303
    const int pair = wid % 36;
    const int kchunk = wid / 36;                  // 0..63
    int sa = 0, rem = pair;
    while (rem >= 8 - sa) { rem -= 8 - sa; ++sa; }
    const int sb = sa + rem;                      // sa <= sb
    const int a0 = sa * 32, b0 = sb * 32;
    const int j0 = kchunk * (NSUP / NKC);
    const int q = l >> 4, ln = l & 15;

    floatx4 acc00 = {0.f, 0.f, 0.f, 0.f}, acc01 = acc00, acc10 = acc00, acc11 = acc00;

    for (int ks = 0; ks < (NSUP / NKC) / 32; ++ks) {   // 4 iterations
        const int jb = j0 + ks * 32 + q * 8;
        float wv[8], a0v[8], a1v[8], b0v[8], b1v[8];
#pragma unroll
        for (int jj = 0; jj < 8; ++jj) {
            const float* row = S + (size_t)(jb + jj) * D;
            wv[jj] = weights[colseg[jb + jj]];
            a0v[jj] = row[a0 + ln];
            a1v[jj] = row[a0 + 16 + ln];
            b0v[jj] = row[b0 + ln];
            b1v[jj] = row[b0 + 16 + ln];
        }
        short8 fa0, fa1, fb0, fb1;
#pragma unroll
        for (int jj = 0; jj < 8; ++jj) {
            fa0[jj] = (short)f2bf(a0v[jj] * wv[jj]);
            fa1[jj] = (short)f2bf(a1v[jj] * wv[jj]);
            fb0[jj] = (short)f2bf(b0v[jj]);
            fb1[jj] = (short)f2bf(b1v[jj]);
        }
        acc00 = __builtin_amdgcn_mfma_f32_16x16x32_bf16(fa0, fb0, acc00, 0, 0, 0);
        acc01 = __builtin_amdgcn_mfma_f32_16x16x32_bf16(fa0, fb1, acc01, 0, 0, 0);
        acc10 = __builtin_amdgcn_mfma_f32_16x16x32_bf16(fa1, fb0, acc10, 0, 0, 0);
        acc11 = __builtin_amdgcn_mfma_f32_16x16x32_bf16(fa1, fb1, acc11, 0, 0, 0);
    }

    float* Mp = Mpart + (size_t)kchunk * (D * D);
#pragma unroll
    for (int r = 0; r < 4; ++r) {
        Mp[(a0 + q * 4 + r) * D + b0 + ln] = acc00[r];
        Mp[(a0 + q * 4 + r) * D + b0 + 16 + ln] = acc01[r];
        Mp[(a0 + 16 + q * 4 + r) * D + b0 + ln] = acc10[r];
        Mp[(a0 + 16 + q * 4 + r) * D + b0 + 16 + ln] = acc11[r];
    }
}

// One block per upper tile (36 blocks). Sum NKC partials with coalesced float4
// loads (unroll-16 ILP), stage summed tile in LDS, emit swizzled bf16 for the
// upper tile AND its transposed mirror:
// Mswz[((q*8+kc)*64+l)*8 + j] = bf16(M[q*16+(l&15)][kc*32+(l>>4)*8+j]).
// Block 0 also zeroes out[512] (k2 accumulates atomically after this kernel).
__global__ __launch_bounds__(256) void kB_sumswz(const float* __restrict__ Mpart,
                                                 unsigned short* __restrict__ Mswz,
                                                 float* __restrict__ out) {
    __shared__ __align__(16) float sm[32][36];
    const int t = threadIdx.x;
    const int p = blockIdx.x;
    if (p == 0) { out[t] = 0.0f; out[t + 256] = 0.0f; }
    int sa = 0, rem = p;
    while (rem >= 8 - sa) { rem -= 8 - sa; ++sa; }
    const int sb = sa + rem;                      // sa <= sb
    const int a0 = sa * 32, b0 = sb * 32;
    {
        const int rl = t >> 3, fg = t & 7;        // 32 rows x 8 float4
        const float* src = Mpart + (size_t)(a0 + rl) * D + b0 + fg * 4;
        float4 acc = make_float4(0.f, 0.f, 0.f, 0.f);
#pragma unroll 16
        for (int c = 0; c < NKC; ++c) {
            float4 u = *(const float4*)(src + (size_t)c * (D * D));
            acc.x += u.x; acc.y += u.y; acc.z += u.z; acc.w += u.w;
        }
        *(float4*)&sm[rl][fg * 4] = acc;
    }
    __syncthreads();

    const int h = t & 127;
    const int rl = h >> 2, cg = h & 3;            // 32 rows x 4 col-groups of 8
    const bool mir = t >= 128;                    // wave-uniform (waves 2,3)
    if (mir && sa == sb) return;                  // diagonal tile: no mirror
    float v[8];
#pragma unroll
    for (int jj = 0; jj < 8; ++jj)
        v[jj] = mir ? sm[cg * 8 + jj][rl] : sm[rl][cg * 8 + jj];
    const int r = (mir ? b0 : a0) + rl;
    const int c = (mir ? a0 : b0) + cg * 8;
    const size_t base = (size_t)(((r >> 4) * 8 + (c >> 5)) * 64 + ((c >> 3) & 3) * 16 + (r & 15)) * 8;
    *(ushort4*)&Mswz[base] = make_ushort4(f2bf(v[0]), f2bf(v[1]), f2bf(v[2]), f2bf(v[3]));
    *(ushort4*)&Mswz[base + 4] = make_ushort4(f2bf(v[4]), f2bf(v[5]), f2bf(v[6]), f2bf(v[7]));
}

// e_i = (p_i^T M p_i)/||p_i||^2 ; out[rowseg[i]] += e_i
// grid: 512 blocks x 64 atoms; wave w owns n-quarter [64w,64w+64).
// kc-OUTER loop: acc[4][4] (64 VGPR) resident; af/bf only live per kc step.
// launch_bounds(256,2): 256-VGPR budget, no spill; 512 blocks = exactly 2/CU.
__global__ __launch_bounds__(256, 2) void k2_quad(const float* __restrict__ P,
                                                  const unsigned short* __restrict__ Mswz,
                                                  const int* __restrict__ rowseg,
                                                  float* __restrict__ out) {
    __shared__ __align__(16) unsigned short Pt[64][264];
    __shared__ float norms[64];
    __shared__ float esh[4][64];
    const int tid = threadIdx.x;
    const int l = tid & 63, w = tid >> 6;
    const int i0 = blockIdx.x * 64;

    // stage Pt: one full atom row (1 KB) per wave-instruction, coalesced
    float np[16];
#pragma unroll
    for (int i = 0; i < 16; ++i) {
        const int row = w + 4 * i;
        float4 v = *(const float4*)&P[(size_t)(i0 + row) * D + 4 * l];
        np[i] = v.x * v.x + v.y * v.y + v.z * v.z + v.w * v.w;
        *(ushort4*)&Pt[row][4 * l] = make_ushort4(f2bf(v.x), f2bf(v.y), f2bf(v.z), f2bf(v.w));
    }
#pragma unroll
    for (int i = 0; i < 16; ++i) {
        float s = np[i];
#pragma unroll
        for (int off = 1; off < 64; off <<= 1) s += __shfl_xor(s, off);
        if (l == 0) norms[w + 4 * i] = s;
    }
    __syncthreads();

    floatx4 acc[4][4];   // [g: m-group][nt: n-tile]
#pragma unroll
    for (int g = 0; g < 4; ++g)
#pragma unroll
        for (int nt = 0; nt < 4; ++nt) acc[g][nt] = (floatx4){0.f, 0.f, 0.f, 0.f};

#pragma unroll 2
    for (int kc = 0; kc < 8; ++kc) {
        short8 bf[4], af[4];
#pragma unroll
        for (int nt = 0; nt < 4; ++nt)
            bf[nt] = *(const short8*)&Mswz[(size_t)(((w * 4 + nt) * 8 + kc) * 64 + l) * 8];
#pragma unroll
        for (int g = 0; g < 4; ++g)
            af[g] = *(const short8*)&Pt[g * 16 + (l & 15)][kc * 32 + (l >> 4) * 8];
#pragma unroll
        for (int g = 0; g < 4; ++g)
#pragma unroll
            for (int nt = 0; nt < 4; ++nt)
                acc[g][nt] = __builtin_amdgcn_mfma_f32_16x16x32_bf16(af[g], bf[nt], acc[g][nt], 0, 0, 0);
    }

    // e[g][r] = sum_n (M p)_n * p_n  (per-atom dot, n split over nt and 16 lanes)
    float e[4][4] = {};
#pragma unroll
    for (int nt = 0; nt < 4; ++nt) {
        const int colg = w * 64 + nt * 16 + (l & 15);
#pragma unroll
        for (int g = 0; g < 4; ++g)
#pragma unroll
            for (int r = 0; r < 4; ++r)
                e[g][r] += acc[g][nt][r] * bf2f(Pt[g * 16 + (l >> 4) * 4 + r][colg]);
    }

    // reduce over the 16 n-lanes
#pragma unroll
    for (int off = 1; off < 16; off <<= 1)
#pragma unroll
        for (int g = 0; g < 4; ++g)
#pragma unroll
            for (int r = 0; r < 4; ++r) e[g][r] += __shfl_xor(e[g][r], off);

    if ((l & 15) == 0) {
#pragma unroll
        for (int g = 0; g < 4; ++g)
#pragma unroll
            for (int r = 0; r < 4; ++r)
                esh[w][g * 16 + (l >> 4) * 4 + r] = e[g][r];
    }
    __syncthreads();

    // segmented reduction over sorted rowseg: tail lane of each run atomics once
    if (tid < 64) {
        float val = (esh[0][tid] + esh[1][tid] + esh[2][tid] + esh[3][tid]) / norms[tid];
        const int seg = rowseg[i0 + tid];
#pragma unroll
        for (int off = 1; off < 64; off <<= 1) {
            float v = __shfl_up(val, off);
            int s2 = __shfl_up(seg, off);
            if (tid >= off && s2 == seg) val += v;
        }
        int segnext = __shfl_down(seg, 1);
        if (tid == 63 || segnext != seg) atomicAdd(&out[seg], val);
    }
}

extern "C" void kernel_launch(void* const* d_in, const int* in_sizes, int n_in,
                              void* d_out, int out_size, void* d_ws, size_t ws_size,
                              hipStream_t stream) {
    const float* P = (const float*)d_in[0];
    const float* S = (const float*)d_in[1];
    const float* W = (const float*)d_in[2];
    const int* rowseg = (const int*)d_in[3];
    const int* colseg = (const int*)d_in[4];
    float* out = (float*)d_out;

    float* Mpart = (float*)d_ws;                                              // NKC x 65536 fp32
    unsigned short* Mswz = (unsigned short*)((char*)d_ws + (size_t)NKC * D * D * 4);  // 65536 bf16

    kA_buildM<<<dim3(NKC * 36 / 4), dim3(256), 0, stream>>>(S, W, colseg, Mpart);
    kB_sumswz<<<dim3(36), dim3(256), 0, stream>>>(Mpart, Mswz, out);
    k2_quad<<<dim3(NATOMS / 64), dim3(256), 0, stream>>>(P, Mswz, rowseg, out);
}

// Round 2
// 106.386 us; speedup vs baseline: 1.0518x; 1.0192x over previous
//
#include <hip/hip_runtime.h>
#include <hip/hip_bf16.h>

#define D 256
#define NATOMS 32768
#define NSUP 8192
#define NSTRUCT 512
#define NKC 64   // k-chunks in kA

typedef __attribute__((ext_vector_type(8))) short short8;
typedef __attribute__((ext_vector_type(4))) float floatx4;

union S8 { short8 s; uint4 u; };

__device__ __forceinline__ unsigned short f2bf(float f) {
    unsigned int u = __float_as_uint(f);
    u += 0x7FFF + ((u >> 16) & 1);   // round-to-nearest-even
    return (unsigned short)(u >> 16);
}
__device__ __forceinline__ float bf2f(unsigned short h) {
    return __uint_as_float(((unsigned int)h) << 16);
}
// packed RTNE f32x2 -> bf16x2 (compiler emits v_cvt_pk_bf16_f32; bit-identical to f2bf)
__device__ __forceinline__ unsigned int cvtpk(float a, float b) {
    __hip_bfloat162 h = __float22bfloat162_rn(make_float2(a, b));
    unsigned int u;
    __builtin_memcpy(&u, &h, 4);
    return u;
}

// ws layout (bytes): Mpart fp32 [NKC][65536] at 0 (16 MB) | Mswz u16 after (128 KB)

// M partials: Mpart[kc][a][b] = sum_{j in chunk kc} w[colseg[j]]*S[j][a]*S[j][b],
// upper slab-triangle only. Wave = 32x32 tile, K-chunk 128. NON-ATOMIC stores to
// disjoint (pair,kchunk) regions. 36 pairs x 64 kchunks = 2304 waves = 576 blocks.
__global__ __launch_bounds__(256) void kA_buildM(const float* __restrict__ S,
                                                 const float* __restrict__ weights,
                                                 const int* __restrict__ colseg,
                                                 float* __restrict__ Mpart) {
    const int tid = threadIdx.x;
    const int l = tid & 63, w = tid >> 6;
    const int wid = blockIdx.x * 4 + w;           // 0..2303
    const int pair = wid % 36;
    const int kchunk = wid / 36;                  // 0..63
    int sa = 0, rem = pair;
    while (rem >= 8 - sa) { rem -= 8 - sa; ++sa; }
    const int sb = sa + rem;                      // sa <= sb
    const int a0 = sa * 32, b0 = sb * 32;
    const int j0 = kchunk * (NSUP / NKC);
    const int q = l >> 4, ln = l & 15;

    floatx4 acc00 = {0.f, 0.f, 0.f, 0.f}, acc01 = acc00, acc10 = acc00, acc11 = acc00;

    for (int ks = 0; ks < (NSUP / NKC) / 32; ++ks) {   // 4 iterations
        const int jb = j0 + ks * 32 + q * 8;
        float wv[8], a0v[8], a1v[8], b0v[8], b1v[8];
#pragma unroll
        for (int jj = 0; jj < 8; ++jj) {
            const float* row = S + (size_t)(jb + jj) * D;
            wv[jj] = weights[colseg[jb + jj]];
            a0v[jj] = row[a0 + ln];
            a1v[jj] = row[a0 + 16 + ln];
            b0v[jj] = row[b0 + ln];
            b1v[jj] = row[b0 + 16 + ln];
        }
        S8 fa0, fa1, fb0, fb1;
        unsigned int pa0[4], pa1[4], pb0[4], pb1[4];
#pragma unroll
        for (int k = 0; k < 4; ++k) {
            pa0[k] = cvtpk(a0v[2 * k] * wv[2 * k], a0v[2 * k + 1] * wv[2 * k + 1]);
            pa1[k] = cvtpk(a1v[2 * k] * wv[2 * k], a1v[2 * k + 1] * wv[2 * k + 1]);
            pb0[k] = cvtpk(b0v[2 * k], b0v[2 * k + 1]);
            pb1[k] = cvtpk(b1v[2 * k], b1v[2 * k + 1]);
        }
        fa0.u = make_uint4(pa0[0], pa0[1], pa0[2], pa0[3]);
        fa1.u = make_uint4(pa1[0], pa1[1], pa1[2], pa1[3]);
        fb0.u = make_uint4(pb0[0], pb0[1], pb0[2], pb0[3]);
        fb1.u = make_uint4(pb1[0], pb1[1], pb1[2], pb1[3]);
        acc00 = __builtin_amdgcn_mfma_f32_16x16x32_bf16(fa0.s, fb0.s, acc00, 0, 0, 0);
        acc01 = __builtin_amdgcn_mfma_f32_16x16x32_bf16(fa0.s, fb1.s, acc01, 0, 0, 0);
        acc10 = __builtin_amdgcn_mfma_f32_16x16x32_bf16(fa1.s, fb0.s, acc10, 0, 0, 0);
        acc11 = __builtin_amdgcn_mfma_f32_16x16x32_bf16(fa1.s, fb1.s, acc11, 0, 0, 0);
    }

    float* Mp = Mpart + (size_t)kchunk * (D * D);
#pragma unroll
    for (int r = 0; r < 4; ++r) {
        Mp[(a0 + q * 4 + r) * D + b0 + ln] = acc00[r];
        Mp[(a0 + q * 4 + r) * D + b0 + 16 + ln] = acc01[r];
        Mp[(a0 + 16 + q * 4 + r) * D + b0 + ln] = acc10[r];
        Mp[(a0 + 16 + q * 4 + r) * D + b0 + 16 + ln] = acc11[r];
    }
}

// 144 blocks = 36 upper tiles x 4 quarter-tiles (16x16). Each block sums its
// quarter over all NKC partials (coalesced 64B segments, unroll-16 ILP),
// stages in LDS, then emits swizzled bf16 for the upper quarter AND its
// transposed mirror:
// Mswz[((q*8+kc)*64+l)*8 + j] = bf16(M[q*16+(l&15)][kc*32+(l>>4)*8+j]).
// Block 0 also zeroes out[512] (k2 accumulates atomically after this kernel).
__global__ __launch_bounds__(256) void kB_sumswz(const float* __restrict__ Mpart,
                                                 unsigned short* __restrict__ Mswz,
                                                 float* __restrict__ out) {
    __shared__ float sm[16][17];
    const int t = threadIdx.x;
    const int p = blockIdx.x >> 2;                // tile 0..35
    const int quad = blockIdx.x & 3;
    const int qr = quad >> 1, qc = quad & 1;
    if (blockIdx.x == 0) { out[t] = 0.0f; out[t + 256] = 0.0f; }
    int sa = 0, rem = p;
    while (rem >= 8 - sa) { rem -= 8 - sa; ++sa; }
    const int sb = sa + rem;                      // sa <= sb
    const int r0 = sa * 32 + qr * 16, c0 = sb * 32 + qc * 16;
    {
        const int rr = t >> 4, cc = t & 15;
        const float* src = Mpart + (size_t)(r0 + rr) * D + (c0 + cc);
        float s = 0.f;
#pragma unroll 16
        for (int c = 0; c < NKC; ++c) s += src[(size_t)c * (D * D)];
        sm[rr][cc] = s;
    }
    __syncthreads();

    if (t < 32) {                                 // upper-quarter emit
        const int rl = t >> 1, cg = t & 1;
        const int r = r0 + rl, c = c0 + cg * 8;
        unsigned int u0 = cvtpk(sm[rl][cg * 8 + 0], sm[rl][cg * 8 + 1]);
        unsigned int u1 = cvtpk(sm[rl][cg * 8 + 2], sm[rl][cg * 8 + 3]);
        unsigned int u2 = cvtpk(sm[rl][cg * 8 + 4], sm[rl][cg * 8 + 5]);
        unsigned int u3 = cvtpk(sm[rl][cg * 8 + 6], sm[rl][cg * 8 + 7]);
        const size_t base = (size_t)(((r >> 4) * 8 + (c >> 5)) * 64 + ((c >> 3) & 3) * 16 + (r & 15)) * 8;
        *(uint4*)&Mswz[base] = make_uint4(u0, u1, u2, u3);
    } else if (t < 64 && sa != sb) {              // mirror emit (transpose)
        const int x = (t - 32) >> 1, g = (t - 32) & 1;
        const int r = c0 + x, c = r0 + g * 8;
        unsigned int u0 = cvtpk(sm[g * 8 + 0][x], sm[g * 8 + 1][x]);
        unsigned int u1 = cvtpk(sm[g * 8 + 2][x], sm[g * 8 + 3][x]);
        unsigned int u2 = cvtpk(sm[g * 8 + 4][x], sm[g * 8 + 5][x]);
        unsigned int u3 = cvtpk(sm[g * 8 + 6][x], sm[g * 8 + 7][x]);
        const size_t base = (size_t)(((r >> 4) * 8 + (c >> 5)) * 64 + ((c >> 3) & 3) * 16 + (r & 15)) * 8;
        *(uint4*)&Mswz[base] = make_uint4(u0, u1, u2, u3);
    }
}

// e_i = (p_i^T M p_i)/||p_i||^2 ; out[rowseg[i]] += e_i
// grid: 512 blocks x 64 atoms; wave w owns n-quarter [64w,64w+64).
// kc-OUTER loop: acc[4][4] (64 VGPR) resident; af/bf only live per kc step.
__global__ __launch_bounds__(256, 2) void k2_quad(const float* __restrict__ P,
                                                  const unsigned short* __restrict__ Mswz,
                                                  const int* __restrict__ rowseg,
                                                  float* __restrict__ out) {
    __shared__ __align__(16) unsigned short Pt[64][264];
    __shared__ float norms[64];
    __shared__ float esh[4][64];
    const int tid = threadIdx.x;
    const int l = tid & 63, w = tid >> 6;
    const int i0 = blockIdx.x * 64;

    // stage Pt: one full atom row (1 KB) per wave-instruction, coalesced
    float np[16];
#pragma unroll
    for (int i = 0; i < 16; ++i) {
        const int row = w + 4 * i;
        float4 v = *(const float4*)&P[(size_t)(i0 + row) * D + 4 * l];
        np[i] = v.x * v.x + v.y * v.y + v.z * v.z + v.w * v.w;
        *(uint2*)&Pt[row][4 * l] = make_uint2(cvtpk(v.x, v.y), cvtpk(v.z, v.w));
    }
#pragma unroll
    for (int i = 0; i < 16; ++i) {
        float s = np[i];
#pragma unroll
        for (int off = 1; off < 64; off <<= 1) s += __shfl_xor(s, off);
        if (l == 0) norms[w + 4 * i] = s;
    }
    __syncthreads();

    floatx4 acc[4][4];   // [g: m-group][nt: n-tile]
#pragma unroll
    for (int g = 0; g < 4; ++g)
#pragma unroll
        for (int nt = 0; nt < 4; ++nt) acc[g][nt] = (floatx4){0.f, 0.f, 0.f, 0.f};

#pragma unroll 2
    for (int kc = 0; kc < 8; ++kc) {
        short8 bf[4], af[4];
#pragma unroll
        for (int nt = 0; nt < 4; ++nt)
            bf[nt] = *(const short8*)&Mswz[(size_t)(((w * 4 + nt) * 8 + kc) * 64 + l) * 8];
#pragma unroll
        for (int g = 0; g < 4; ++g)
            af[g] = *(const short8*)&Pt[g * 16 + (l & 15)][kc * 32 + (l >> 4) * 8];
#pragma unroll
        for (int g = 0; g < 4; ++g)
#pragma unroll
            for (int nt = 0; nt < 4; ++nt)
                acc[g][nt] = __builtin_amdgcn_mfma_f32_16x16x32_bf16(af[g], bf[nt], acc[g][nt], 0, 0, 0);
    }

    // e[g][r] = sum_n (M p)_n * p_n  (per-atom dot, n split over nt and 16 lanes)
    float e[4][4] = {};
#pragma unroll
    for (int nt = 0; nt < 4; ++nt) {
        const int colg = w * 64 + nt * 16 + (l & 15);
#pragma unroll
        for (int g = 0; g < 4; ++g)
#pragma unroll
            for (int r = 0; r < 4; ++r)
                e[g][r] += acc[g][nt][r] * bf2f(Pt[g * 16 + (l >> 4) * 4 + r][colg]);
    }

    // reduce over the 16 n-lanes
#pragma unroll
    for (int off = 1; off < 16; off <<= 1)
#pragma unroll
        for (int g = 0; g < 4; ++g)
#pragma unroll
            for (int r = 0; r < 4; ++r) e[g][r] += __shfl_xor(e[g][r], off);

    if ((l & 15) == 0) {
#pragma unroll
        for (int g = 0; g < 4; ++g)
#pragma unroll
            for (int r = 0; r < 4; ++r)
                esh[w][g * 16 + (l >> 4) * 4 + r] = e[g][r];
    }
    __syncthreads();

    // segmented reduction over sorted rowseg: tail lane of each run atomics once
    if (tid < 64) {
        float val = (esh[0][tid] + esh[1][tid] + esh[2][tid] + esh[3][tid]) / norms[tid];
        const int seg = rowseg[i0 + tid];
#pragma unroll
        for (int off = 1; off < 64; off <<= 1) {
            float v = __shfl_up(val, off);
            int s2 = __shfl_up(seg, off);
            if (tid >= off && s2 == seg) val += v;
        }
        int segnext = __shfl_down(seg, 1);
        if (tid == 63 || segnext != seg) atomicAdd(&out[seg], val);
    }
}

extern "C" void kernel_launch(void* const* d_in, const int* in_sizes, int n_in,
                              void* d_out, int out_size, void* d_ws, size_t ws_size,
                              hipStream_t stream) {
    const float* P = (const float*)d_in[0];
    const float* S = (const float*)d_in[1];
    const float* W = (const float*)d_in[2];
    const int* rowseg = (const int*)d_in[3];
    const int* colseg = (const int*)d_in[4];
    float* out = (float*)d_out;

    float* Mpart = (float*)d_ws;                                              // NKC x 65536 fp32
    unsigned short* Mswz = (unsigned short*)((char*)d_ws + (size_t)NKC * D * D * 4);  // 65536 bf16

    kA_buildM<<<dim3(NKC * 36 / 4), dim3(256), 0, stream>>>(S, W, colseg, Mpart);
    kB_sumswz<<<dim3(144), dim3(256), 0, stream>>>(Mpart, Mswz, out);
    k2_quad<<<dim3(NATOMS / 64), dim3(256), 0, stream>>>(P, Mswz, rowseg, out);
}